// Round 16
// baseline (140.371 us; speedup 1.0000x reference)
//
#include <hip/hip_runtime.h>
#include <hip/hip_bf16.h>

#define N_NODES 100000
#define N_EDGES 3200000
#define F_IN    512
#define F_H     16
#define F_OUT   7
#define NB      391                 // buckets of 256 dst nodes
#define GPART   512                 // partition blocks
#define PER_BLK 6256                // multiple of 4; 512*6256 >= 3.2M (last block short)
#define NTILES  6250                // 100000 / 16 row-tiles
#define GEMMB   1563                // ceil(NTILES/4) gemm blocks (64 rows each)
#define CAPB    10240               // fixed slot per bucket (mean 8184, sigma~90 -> 22 sigma)
#define NPAD    (NB * 256)          // 100096 padded node count

typedef unsigned int u32;
typedef __attribute__((ext_vector_type(8))) __bf16 bf16x8;
typedef __attribute__((ext_vector_type(4))) float f32x4;

union FragU { uint4 q; bf16x8 v; };

static __device__ __forceinline__ float bflo(u32 u) { return __uint_as_float(u << 16); }
static __device__ __forceinline__ float bfhi(u32 u) { return __uint_as_float(u & 0xFFFF0000u); }
static __device__ __forceinline__ unsigned short f2bf(float f) {
  u32 x = __float_as_uint(f);
  x += 0x7FFF + ((x >> 16) & 1);    // round-to-nearest-even (finite values)
  return (unsigned short)(x >> 16);
}
// pack two fp32 -> two bf16 in one u32 (low16 = a, high16 = b)
static __device__ __forceinline__ u32 cvt2(float a, float b) {
  u32 r;
  asm("v_cvt_pk_bf16_f32 %0, %1, %2" : "=v"(r) : "v"(a), "v"(b));
  return r;
}

// ---- prep (1 block): gcur[b] = b*CAPB  +  W1 bf16 B-fragment table ----
__global__ __launch_bounds__(512) void k_prep(int* __restrict__ gcur,
                                              const float* __restrict__ W1,
                                              uint4* __restrict__ bfragG) {
  int tid = threadIdx.x;
  if (tid < NB) gcur[tid] = tid * CAPB;
  // B-fragment for mfma_f32_16x16x32_bf16: lane l holds B[k=(l>>4)*8+j][col=l&15]
  for (int idx = tid; idx < 1024; idx += 512) {  // 16 kk * 64 lanes
    int kk = idx >> 6, lane = idx & 63;
    int col = lane & 15, g = lane >> 4;
    int k0 = kk * 32 + g * 8;
    uint4 q;
    q.x = cvt2(W1[(k0 + 0) * 16 + col], W1[(k0 + 1) * 16 + col]);
    q.y = cvt2(W1[(k0 + 2) * 16 + col], W1[(k0 + 3) * 16 + col]);
    q.z = cvt2(W1[(k0 + 4) * 16 + col], W1[(k0 + 5) * 16 + col]);
    q.w = cvt2(W1[(k0 + 6) * 16 + col], W1[(k0 + 7) * 16 + col]);
    bfragG[idx] = q;
  }
}

// ==== fused: partition (blocks < GPART) ∥ GEMM1 unfolded (blocks >= GPART) ====
// The two works are independent (gemm no longer folds dinv), so they fill the
// machine concurrently: part is latency/atomic-bound, gemm is HBM-bound.
__global__ __launch_bounds__(256) void k_pg(const int* __restrict__ src,
                                            const int* __restrict__ dst,
                                            int* __restrict__ gcur,
                                            u32* __restrict__ pairs,
                                            const float* __restrict__ x,
                                            const uint4* __restrict__ bfragG,
                                            unsigned short* __restrict__ h1p) {
  __shared__ __align__(16) char smem[10240];     // 10 KB shared by both paths
  int tid = threadIdx.x;

  if (blockIdx.x < GPART) {
    // ---------------- partition path ----------------
    int* h     = (int*)smem;                     // [NB]
    int* lbase = (int*)(smem + 1792);            // [NB] (NB*4=1564, pad to 1792)
    int* lcur  = (int*)(smem + 3584);            // [NB]
    int blk = blockIdx.x;
    for (int b = tid; b < NB; b += 256) h[b] = 0;
    __syncthreads();
    int e0 = blk * PER_BLK;
    int n = min(PER_BLK, N_EDGES - e0);          // multiple of 4
    const int4* s4 = (const int4*)(src + e0);
    const int4* d4 = (const int4*)(dst + e0);
    for (int i = tid; i < (n >> 2); i += 256) {
      int4 d = d4[i];
      atomicAdd(&h[d.x >> 8], 1);
      atomicAdd(&h[d.y >> 8], 1);
      atomicAdd(&h[d.z >> 8], 1);
      atomicAdd(&h[d.w >> 8], 1);
    }
    __syncthreads();
    for (int b = tid; b < NB; b += 256) {
      int c = h[b];
      lbase[b] = c ? atomicAdd(&gcur[b], c) : 0;
      lcur[b] = 0;
    }
    __syncthreads();
    for (int i = tid; i < (n >> 2); i += 256) {
      int4 sv = s4[i];
      int4 dv = d4[i];
      { int b = dv.x >> 8; u32 v = ((u32)(dv.x & 255) << 17) | (u32)sv.x;
        pairs[lbase[b] + atomicAdd(&lcur[b], 1)] = v; }
      { int b = dv.y >> 8; u32 v = ((u32)(dv.y & 255) << 17) | (u32)sv.y;
        pairs[lbase[b] + atomicAdd(&lcur[b], 1)] = v; }
      { int b = dv.z >> 8; u32 v = ((u32)(dv.z & 255) << 17) | (u32)sv.z;
        pairs[lbase[b] + atomicAdd(&lcur[b], 1)] = v; }
      { int b = dv.w >> 8; u32 v = ((u32)(dv.w & 255) << 17) | (u32)sv.w;
        pairs[lbase[b] + atomicAdd(&lcur[b], 1)] = v; }
    }
    return;
  }

  // ---------------- GEMM1 path (unfolded h1p) ----------------
  char (*ldsbuf)[64 * 80] = (char (*)[64 * 80])smem;   // [2][5120]
  int gb = blockIdx.x - GPART;
  int blockRow0 = gb * 64;

  int r0 = tid >> 3, r1 = r0 + 32, s = tid & 7;
  bool ok1 = (blockRow0 + r1) < N_NODES;
  const float* x0 = x + (size_t)(blockRow0 + r0) * F_IN + s * 4;
  const float* x1 = x + (size_t)(blockRow0 + r1) * F_IN + s * 4;

  int wv = tid >> 6, lane = tid & 63;
  int col = lane & 15, g = lane >> 4;
  int wid = gb * 4 + wv;
  int fragRow = wv * 16 + col;

  f32x4 acc = {0.f, 0.f, 0.f, 0.f};

  {
    float4 fA = *(const float4*)(x0);
    float4 fB = ok1 ? *(const float4*)(x1) : make_float4(0.f, 0.f, 0.f, 0.f);
    uint2 qA = {cvt2(fA.x, fA.y), cvt2(fA.z, fA.w)};
    uint2 qB = {cvt2(fB.x, fB.y), cvt2(fB.z, fB.w)};
    *(uint2*)(&ldsbuf[0][r0 * 80 + s * 8]) = qA;
    *(uint2*)(&ldsbuf[0][r1 * 80 + s * 8]) = qB;
  }
  __syncthreads();

#pragma unroll
  for (int kk = 0; kk < 16; kk++) {
    int cur = kk & 1;
    float4 fA, fB;
    if (kk < 15) {
      fA = *(const float4*)(x0 + (kk + 1) * 32);
      fB = ok1 ? *(const float4*)(x1 + (kk + 1) * 32) : make_float4(0.f, 0.f, 0.f, 0.f);
    }
    FragU a, b;
    a.q = *(const uint4*)(&ldsbuf[cur][fragRow * 80 + g * 16]);
    b.q = bfragG[kk * 64 + lane];
    acc = __builtin_amdgcn_mfma_f32_16x16x32_bf16(a.v, b.v, acc, 0, 0, 0);
    if (kk < 15) {
      uint2 qA = {cvt2(fA.x, fA.y), cvt2(fA.z, fA.w)};
      uint2 qB = {cvt2(fB.x, fB.y), cvt2(fB.z, fB.w)};
      *(uint2*)(&ldsbuf[cur ^ 1][r0 * 80 + s * 8]) = qA;
      *(uint2*)(&ldsbuf[cur ^ 1][r1 * 80 + s * 8]) = qB;
    }
    __syncthreads();
  }

  // D: col = lane&15 (feature), row = (lane>>4)*4 + r; store UNFOLDED bf16
#pragma unroll
  for (int r = 0; r < 4; r++) {
    int node = wid * 16 + g * 4 + r;
    if (node < N_NODES) h1p[(size_t)node * F_H + col] = f2bf(acc[r]);
  }
}

// ---- per-bucket degree + excl scan + dinv-fold of h1p rows ----
__global__ __launch_bounds__(256) void k_deg(const u32* __restrict__ pairs,
                                             const int* __restrict__ gcur,
                                             int* __restrict__ dega,
                                             int* __restrict__ excla,
                                             unsigned short* __restrict__ h1p) {
  __shared__ int h[256];
  __shared__ int sc[256];
  int tid = threadIdx.x, b = blockIdx.x;
  h[tid] = 0;
  __syncthreads();
  int base = b * CAPB;
  int cnt = gcur[b] - base;
  for (int k = tid; k < cnt; k += 256)
    atomicAdd(&h[pairs[base + k] >> 17], 1);
  __syncthreads();
  int c = h[tid];
  sc[tid] = c;
  __syncthreads();
  for (int off = 1; off < 256; off <<= 1) {
    int v = (tid >= off) ? sc[tid - off] : 0;
    __syncthreads();
    sc[tid] += v;
    __syncthreads();
  }
  int node = b * 256 + tid;
  dega[node] = c;
  excla[node] = sc[tid] - c;
  if (node < N_NODES) {                          // fold dinv into h1p row
    float di = rsqrtf((float)(c + 1));
    uint4* hp4 = (uint4*)h1p;
    uint4 q0 = hp4[node * 2], q1 = hp4[node * 2 + 1];
    q0.x = cvt2(di * bflo(q0.x), di * bfhi(q0.x));
    q0.y = cvt2(di * bflo(q0.y), di * bfhi(q0.y));
    q0.z = cvt2(di * bflo(q0.z), di * bfhi(q0.z));
    q0.w = cvt2(di * bflo(q0.w), di * bfhi(q0.w));
    q1.x = cvt2(di * bflo(q1.x), di * bfhi(q1.x));
    q1.y = cvt2(di * bflo(q1.y), di * bfhi(q1.y));
    q1.z = cvt2(di * bflo(q1.z), di * bfhi(q1.z));
    q1.w = cvt2(di * bflo(q1.w), di * bfhi(q1.w));
    hp4[node * 2] = q0;
    hp4[node * 2 + 1] = q1;
  }
}

// ====== agg1: scatter col[] (excl precomputed) + node-parallel reduce ======
__global__ __launch_bounds__(512) void k_agg1(const u32* __restrict__ pairs,
                                              const int* __restrict__ gcur,
                                              const int* __restrict__ dega,
                                              const int* __restrict__ excla,
                                              const unsigned short* __restrict__ h1p,
                                              const float* __restrict__ b1,
                                              const float* __restrict__ W2,
                                              unsigned short* __restrict__ gfp) {
  __shared__ u32 col[CAPB];                      // 40 KB grouped src indices
  __shared__ int exc[256];
  __shared__ int dg[256];
  __shared__ int cur[256];
  int tid = threadIdx.x, b = blockIdx.x;
  if (tid < 256) {
    int node = b * 256 + tid;
    dg[tid] = dega[node];
    exc[tid] = excla[node];
    cur[tid] = 0;
  }
  __syncthreads();
  int base = b * CAPB;
  int cnt = gcur[b] - base;
  for (int k = tid; k < cnt; k += 512) {
    u32 v = pairs[base + k];
    int dl = v >> 17;
    col[exc[dl] + atomicAdd(&cur[dl], 1)] = v & 0x1FFFF;
  }
  __syncthreads();

  // node-parallel: thread pair (tid, tid^1) owns node b*256 + (tid>>1);
  // h = tid&1 selects which uint4 half-row (8 feats) this thread gathers.
  int dl = tid >> 1, h = tid & 1;
  int node = b * 256 + dl;
  if (node >= N_NODES) return;                   // whole waves exit together
  int s0 = exc[dl], c0 = dg[dl];
  const uint4* hp = (const uint4*)h1p;
  float a[8] = {0.f, 0.f, 0.f, 0.f, 0.f, 0.f, 0.f, 0.f};
  for (int e = s0; e < s0 + c0; e++) {
    uint4 hv = hp[col[e] * 2 + h];
    a[0] += bflo(hv.x); a[1] += bfhi(hv.x);
    a[2] += bflo(hv.y); a[3] += bfhi(hv.y);
    a[4] += bflo(hv.z); a[5] += bfhi(hv.z);
    a[6] += bflo(hv.w); a[7] += bfhi(hv.w);
  }
  {                                              // self-loop (dinv pre-folded)
    uint4 hv = hp[node * 2 + h];
    a[0] += bflo(hv.x); a[1] += bfhi(hv.x);
    a[2] += bflo(hv.y); a[3] += bfhi(hv.y);
    a[4] += bflo(hv.z); a[5] += bfhi(hv.z);
    a[6] += bflo(hv.w); a[7] += bfhi(hv.w);
  }
  float di = rsqrtf((float)(c0 + 1));
  float own[8];
#pragma unroll
  for (int k = 0; k < 8; k++)
    own[k] = fmaxf(di * a[k] + b1[h * 8 + k], 0.f);
  float oth[8];
#pragma unroll
  for (int k = 0; k < 8; k++) oth[k] = __shfl_xor(own[k], 1, 64);
  if (h == 0) {
    // own = feats 0..7, oth = feats 8..15
    float o[7] = {0.f, 0.f, 0.f, 0.f, 0.f, 0.f, 0.f};
#pragma unroll
    for (int k = 0; k < 8; k++)
#pragma unroll
      for (int j = 0; j < 7; j++)
        o[j] += own[k] * W2[k * 7 + j] + oth[k] * W2[(k + 8) * 7 + j];
    uint4 q;
    q.x = cvt2(di * o[0], di * o[1]);
    q.y = cvt2(di * o[2], di * o[3]);
    q.z = cvt2(di * o[4], di * o[5]);
    q.w = cvt2(di * o[6], 0.f);
    ((uint4*)gfp)[node] = q;
  }
}

// ====== agg2: scatter col[] + 2-thr/node edge-split + softmax epilogue ======
__global__ __launch_bounds__(512) void k_agg2(const u32* __restrict__ pairs,
                                              const int* __restrict__ gcur,
                                              const int* __restrict__ dega,
                                              const int* __restrict__ excla,
                                              const unsigned short* __restrict__ gfp,
                                              const float* __restrict__ b2,
                                              float* __restrict__ out) {
  __shared__ u32 col[CAPB];
  __shared__ int exc[256];
  __shared__ int dg[256];
  __shared__ int cur[256];
  int tid = threadIdx.x, b = blockIdx.x;
  if (tid < 256) {
    int node = b * 256 + tid;
    dg[tid] = dega[node];
    exc[tid] = excla[node];
    cur[tid] = 0;
  }
  __syncthreads();
  int base = b * CAPB;
  int cnt = gcur[b] - base;
  for (int k = tid; k < cnt; k += 512) {
    u32 v = pairs[base + k];
    int dl = v >> 17;
    col[exc[dl] + atomicAdd(&cur[dl], 1)] = v & 0x1FFFF;
  }
  __syncthreads();

  int dl = tid >> 1, h = tid & 1;
  int node = b * 256 + dl;
  if (node >= N_NODES) return;
  int s0 = exc[dl], c0 = dg[dl];
  const uint4* gp = (const uint4*)gfp;
  float a[7] = {0.f, 0.f, 0.f, 0.f, 0.f, 0.f, 0.f};
  for (int e = s0 + h; e < s0 + c0; e += 2) {    // edges split between the pair
    uint4 gv = gp[col[e]];
    a[0] += bflo(gv.x); a[1] += bfhi(gv.x);
    a[2] += bflo(gv.y); a[3] += bfhi(gv.y);
    a[4] += bflo(gv.z); a[5] += bfhi(gv.z);
    a[6] += bflo(gv.w);
  }
#pragma unroll
  for (int j = 0; j < 7; j++) a[j] += __shfl_xor(a[j], 1, 64);
  if (h == 0) {
    uint4 sv = gp[node];                         // self-loop
    a[0] += bflo(sv.x); a[1] += bfhi(sv.x);
    a[2] += bflo(sv.y); a[3] += bfhi(sv.y);
    a[4] += bflo(sv.z); a[5] += bfhi(sv.z);
    a[6] += bflo(sv.w);
    float di = rsqrtf((float)(c0 + 1));
    float v[7];
#pragma unroll
    for (int j = 0; j < 7; j++) v[j] = di * a[j] + b2[j];
    float m = v[0];
#pragma unroll
    for (int j = 1; j < 7; j++) m = fmaxf(m, v[j]);
    float s = 0.f;
#pragma unroll
    for (int j = 0; j < 7; j++) s += __expf(v[j] - m);
    float ls = m + logf(s);
#pragma unroll
    for (int j = 0; j < 7; j++) out[(size_t)node * 7 + j] = v[j] - ls;
  }
}

extern "C" void kernel_launch(void* const* d_in, const int* in_sizes, int n_in,
                              void* d_out, int out_size, void* d_ws, size_t ws_size,
                              hipStream_t stream) {
  const float* x  = (const float*)d_in[0];
  const int*   ei = (const int*)d_in[1];     // [0..E)=src, [E..2E)=dst (int32)
  const float* W1 = (const float*)d_in[2];
  const float* b1 = (const float*)d_in[3];
  const float* W2 = (const float*)d_in[4];
  const float* b2 = (const float*)d_in[5];
  float* out = (float*)d_out;

  // workspace layout (~21.7 MB; d_ws ~800 MB)
  char* base = (char*)d_ws;
  int*   gcur   = (int*)(base + 0);            //      2,048
  uint4* bfragG = (uint4*)(base + 2048);       //     16,384
  int*   dega   = (int*)(base + 18432);        //    400,384 (NPAD*4)
  int*   excla  = (int*)(base + 418816);       //    400,384
  u32*   pairs  = (u32*)(base + 819200);       // 16,015,360 (NB*CAPB*4; ends 16,834,560)
  unsigned short* h1p = (unsigned short*)(base + 16834560); // 3.2 MB (ends 20,034,560)
  unsigned short* gfp = (unsigned short*)(base + 20034560); // 1.6 MB (ends 21,634,560)

  k_prep<<<1, 512, 0, stream>>>(gcur, W1, bfragG);
  k_pg  <<<GPART + GEMMB, 256, 0, stream>>>(ei, ei + N_EDGES, gcur, pairs, x, bfragG, h1p);
  k_deg <<<NB, 256, 0, stream>>>(pairs, gcur, dega, excla, h1p);
  k_agg1<<<NB, 512, 0, stream>>>(pairs, gcur, dega, excla, h1p, b1, W2, gfp);
  k_agg2<<<NB, 512, 0, stream>>>(pairs, gcur, dega, excla, gfp, b2, out);
}